// Round 7
// baseline (133.876 us; speedup 1.0000x reference)
//
#include <hip/hip_runtime.h>
#include <math.h>

// Output layout (float32, concatenated in reference return order):
//   rendered [128,1,28,28]  @ 0       (100352)
//   mu       [128,64]       @ 100352  (8192)
//   logvar   [128,64]       @ 108544  (8192)
//   cp       [128,2,3,4,2]  @ 116736  (6144)
//   widths   [128,2]        @ 122880  (256)
//   alphas   [128,2]        @ 123136  (256)
#define REND_OFF 0
#define MU_OFF   100352
#define LV_OFF   108544
#define CP_OFF   116736
#define W_OFF    122880
#define A_OFF    123136

// int8 weight workspace (u32 units). Layout per layer: u32 array [K/4][N],
// u32 at (g, c) packs biased-uint8 weights {W[4g..4g+3][c] / s_c + 128}.
// Column scales s_c (fp32) follow all weight blocks.
#define U_W1 0        // [208][256]  (K 784 padded to 832)
#define U_W2 53248    // [64][256]
#define U_ML 69632    // [64][128]   (mu|lv fused, N=128)
#define U_D1 77824    // [16][512]
#define U_D2 86016    // [128][512]
#define U_H  151552   // [128][64]   (p|wd|a|pad0)
#define SCOFF 159744  // 1728 fp32 column scales
// scale bases within the 1728-entry scale array:
#define B_W1 0
#define B_W2 256
#define B_ML 512
#define B_D1 640
#define B_D2 1152
#define B_H  1664
#define NCOLS 1728

__device__ __forceinline__ float leakyf(float x) {
    return x >= 0.f ? x : 0.2f * x;
}
__device__ __forceinline__ float seluf(float x) {
    const float sc = 1.0507009873554805f;
    const float al = 1.6732632423543772f;
    return x > 0.f ? sc * x : sc * al * expm1f(x);
}
__device__ __forceinline__ float sigmoidf(float x) {
    return 1.f / (1.f + expf(-x));
}
// biased-uint8 lane extraction -> float (compiler emits v_cvt_f32_ubyteN)
__device__ __forceinline__ float ub0(unsigned w) { return (float)(w & 0xffu); }
__device__ __forceinline__ float ub1(unsigned w) { return (float)((w >> 8) & 0xffu); }
__device__ __forceinline__ float ub2(unsigned w) { return (float)((w >> 16) & 0xffu); }
__device__ __forceinline__ float ub3(unsigned w) { return (float)(w >> 24); }

// ---- kernel 0: per-column max + int8 quantize into tiled layout ----
// One wave per column; grid 432 x 256 (4 waves/block), 1728 columns total.
__global__ __launch_bounds__(256) void conv_q(
    const float* __restrict__ e_w1, const float* __restrict__ e_w2,
    const float* __restrict__ w_mu, const float* __restrict__ w_lv,
    const float* __restrict__ d_w1, const float* __restrict__ d_w2,
    const float* __restrict__ p_w,  const float* __restrict__ wd_w,
    const float* __restrict__ a_w,  unsigned* __restrict__ wsu)
{
    const int col  = blockIdx.x * 4 + (threadIdx.x >> 6);
    const int lane = threadIdx.x & 63;
    if (col >= NCOLS) return;

    int K, G, N, base, c;
    const float* src = nullptr;
    int stride = 0;
    // layer resolve
    if (col < 256)       { c = col;        K = 784; G = 208; N = 256; base = U_W1; src = e_w1 + c; stride = 256; }
    else if (col < 512)  { c = col - 256;  K = 256; G = 64;  N = 256; base = U_W2; src = e_w2 + c; stride = 256; }
    else if (col < 640)  { c = col - 512;  K = 256; G = 64;  N = 128; base = U_ML;
                           src = (c < 64) ? (w_mu + c) : (w_lv + c - 64); stride = 64; }
    else if (col < 1152) { c = col - 640;  K = 64;  G = 16;  N = 512; base = U_D1; src = d_w1 + c; stride = 512; }
    else if (col < 1664) { c = col - 1152; K = 512; G = 128; N = 512; base = U_D2; src = d_w2 + c; stride = 512; }
    else                 { c = col - 1664; K = 512; G = 128; N = 64;  base = U_H;
                           if (c < 40)      { src = p_w + c;        stride = 40; }
                           else if (c < 42) { src = wd_w + (c - 40); stride = 2; }
                           else if (c < 44) { src = a_w + (c - 42);  stride = 2; }
                           else             { src = nullptr; } }

    // pass 1: column absmax
    float m = 0.f;
    if (src) {
        for (int k = lane; k < K; k += 64)
            m = fmaxf(m, fabsf(src[k * stride]));
    }
    #pragma unroll
    for (int d = 1; d < 64; d <<= 1)
        m = fmaxf(m, __shfl_xor(m, d));
    const float inv = (m > 0.f) ? 127.f / m : 0.f;
    const float scale = m / 127.f;

    // pass 2: quantize + pack 4 k's per u32
    const int colN = col - ((col < 256) ? 0 : (col < 512) ? 256 : (col < 640) ? 512
                     : (col < 1152) ? 640 : (col < 1664) ? 1152 : 1664);
    for (int g = lane; g < G; g += 64) {
        unsigned u = 0;
        #pragma unroll
        for (int e = 0; e < 4; ++e) {
            int k = 4 * g + e;
            float w = (src && k < K) ? src[k * stride] : 0.f;
            float qf = rintf(w * inv);
            qf = fminf(127.f, fmaxf(-127.f, qf));
            unsigned b = (unsigned)((int)qf + 128);
            u |= b << (8 * e);
        }
        wsu[base + g * N + colN] = u;
    }
    if (lane == 0)
        ((float*)(wsu + SCOFF))[col] = scale;
}

// ---- int8 layer slice GEMM: 16B weight loads (16 weights), fp32 acts ----
// N cols, JG = N/4 col groups, S = 1024/JG k-slices, G k-groups (4k) each.
template<int N, int JG, int S, int G>
__device__ __forceinline__ void i8gemm(const uint4* __restrict__ wq,
                                       const float* __restrict__ xf,
                                       float* __restrict__ red, int tid)
{
    constexpr int NTp = N + 4;
    const int jg = tid % JG, ks = tid / JG;
    const uint4* wp = wq + (ks * G) * (N / 4) + jg;
    const float4* xp = (const float4*)xf + ks * G;
    float a0 = 0.f, a1 = 0.f, a2 = 0.f, a3 = 0.f, sx = 0.f;
    #pragma unroll 8
    for (int g = 0; g < G; ++g) {
        uint4 w = wp[g * (N / 4)];
        float4 xv = xp[g];
        sx += (xv.x + xv.y) + (xv.z + xv.w);
        a0 = fmaf(ub0(w.x), xv.x, a0); a0 = fmaf(ub1(w.x), xv.y, a0);
        a0 = fmaf(ub2(w.x), xv.z, a0); a0 = fmaf(ub3(w.x), xv.w, a0);
        a1 = fmaf(ub0(w.y), xv.x, a1); a1 = fmaf(ub1(w.y), xv.y, a1);
        a1 = fmaf(ub2(w.y), xv.z, a1); a1 = fmaf(ub3(w.y), xv.w, a1);
        a2 = fmaf(ub0(w.z), xv.x, a2); a2 = fmaf(ub1(w.z), xv.y, a2);
        a2 = fmaf(ub2(w.z), xv.z, a2); a2 = fmaf(ub3(w.z), xv.w, a2);
        a3 = fmaf(ub0(w.w), xv.x, a3); a3 = fmaf(ub1(w.w), xv.y, a3);
        a3 = fmaf(ub2(w.w), xv.z, a3); a3 = fmaf(ub3(w.w), xv.w, a3);
    }
    const float bias = -128.f * sx;   // undo the +128 weight bias
    *(float4*)&red[ks * NTp + 4 * jg] =
        make_float4(a0 + bias, a1 + bias, a2 + bias, a3 + bias);
}

template<int N, int S, int ACT>
__device__ __forceinline__ void reduce_i8(const float* __restrict__ red,
                                          const float* __restrict__ scl,
                                          const float* __restrict__ bias,
                                          float* __restrict__ Cf, int tid)
{
    constexpr int NTp = N + 4;
    if (tid < N) {
        float s = 0.f;
        #pragma unroll
        for (int si = 0; si < S; ++si) s += red[si * NTp + tid];
        float v = fmaf(scl[tid], s, bias[tid]);
        Cf[tid] = (ACT == 1) ? leakyf(v) : seluf(v);
    }
}

// ---- fused MLP: 128 blocks x 1024 thr; 1 batch elem per block ----
__global__ __launch_bounds__(1024) void vae_mlp(
    const float* __restrict__ x,    const float* __restrict__ eps,
    const float* __restrict__ e_b1, const float* __restrict__ e_b2,
    const float* __restrict__ b_mu, const float* __restrict__ b_lv,
    const float* __restrict__ d_b1, const float* __restrict__ d_b2,
    const float* __restrict__ p_b,  const float* __restrict__ wd_b,
    const float* __restrict__ a_b,
    const unsigned* __restrict__ wsu, float* __restrict__ out)
{
    const int b   = blockIdx.x;
    const int tid = threadIdx.x;

    __shared__ __align__(16) float xs[832];     // fp32, K padded to 832
    __shared__ __align__(16) float h1f[256];
    __shared__ __align__(16) float h2f[256];
    __shared__ __align__(16) float zf[64];
    __shared__ __align__(16) float d1f[512];
    __shared__ __align__(16) float d2f[512];
    __shared__ float mulv[128];
    __shared__ float pts[40];
    __shared__ float scl[NCOLS];                // all column scales
    __shared__ __align__(16) float red[4352];   // max: heads 64*68

    if (tid < 832) xs[tid] = (tid < 784) ? x[b * 784 + tid] : 0.f;
    for (int i = tid; i < NCOLS; i += 1024)
        scl[i] = ((const float*)(wsu + SCOFF))[i];
    __syncthreads();

    // encoder L1: K=832(pad), N=256
    i8gemm<256, 64, 16, 13>((const uint4*)(wsu + U_W1), xs, red, tid);
    __syncthreads();
    reduce_i8<256, 16, 1>(red, scl + B_W1, e_b1, h1f, tid);
    __syncthreads();

    // encoder L2: K=256, N=256
    i8gemm<256, 64, 16, 4>((const uint4*)(wsu + U_W2), h1f, red, tid);
    __syncthreads();
    reduce_i8<256, 16, 1>(red, scl + B_W2, e_b2, h2f, tid);
    __syncthreads();

    // mu|logvar: K=256, N=128 + reparameterization
    i8gemm<128, 32, 32, 2>((const uint4*)(wsu + U_ML), h2f, red, tid);
    __syncthreads();
    if (tid < 128) {
        float s = 0.f;
        #pragma unroll
        for (int si = 0; si < 32; ++si) s += red[si * 132 + tid];
        float v = fmaf(scl[B_ML + tid], s,
                       (tid < 64) ? b_mu[tid] : b_lv[tid - 64]);
        mulv[tid] = v;
        out[(tid < 64 ? MU_OFF : LV_OFF) + b * 64 + (tid & 63)] = v;
    }
    __syncthreads();
    if (tid < 64) {
        zf[tid] = fmaf(eps[b * 64 + tid], expf(0.5f * mulv[64 + tid]), mulv[tid]);
    }
    __syncthreads();

    // decoder L1: K=64, N=512
    i8gemm<512, 128, 8, 2>((const uint4*)(wsu + U_D1), zf, red, tid);
    __syncthreads();
    reduce_i8<512, 8, 2>(red, scl + B_D1, d_b1, d1f, tid);
    __syncthreads();

    // decoder L2: K=512, N=512
    i8gemm<512, 128, 8, 16>((const uint4*)(wsu + U_D2), d1f, red, tid);
    __syncthreads();
    reduce_i8<512, 8, 2>(red, scl + B_D2, d_b2, d2f, tid);
    __syncthreads();

    // heads: K=512, N=64 (44 live)
    i8gemm<64, 16, 64, 2>((const uint4*)(wsu + U_H), d2f, red, tid);
    __syncthreads();
    if (tid < 44) {
        float s = 0.f;
        #pragma unroll
        for (int si = 0; si < 64; ++si) s += red[si * 68 + tid];
        s *= scl[B_H + tid];
        if (tid < 40) {
            pts[tid] = tanhf(s + p_b[tid]) * 12.f + 14.f;   // CANVAS/2-MARGIN
        } else if (tid < 42) {
            out[W_OFF + b * 2 + (tid - 40)] =
                sigmoidf(s + wd_b[tid - 40]) * 2.f + 1.f;
        } else {
            out[A_OFF + b * 2 + (tid - 42)] = sigmoidf(s + a_b[tid - 42]);
        }
    }
    __syncthreads();

    // scatter cp [P=2,S=3,4,2] from pts [P=2,PPP=10,2]
    if (tid < 48) {
        int p = tid / 24, rem = tid % 24;
        int s = rem / 8, kc = rem % 8;
        int k = kc >> 1, c = kc & 1;
        out[CP_OFF + b * 48 + tid] = pts[p * 20 + (3 * s + k) * 2 + c];
    }
}

// ---- render: grid (128, 4), 256 threads; block (b,q) -> pixel rows 7q.. ----
__global__ __launch_bounds__(256) void vae_render(float* __restrict__ out)
{
    const int b   = blockIdx.x;
    const int q   = blockIdx.y;
    const int tid = threadIdx.x;

    __shared__ float2 cur[192];
    __shared__ float  wa[4];

    if (tid < 192) {
        int p = tid / 96;
        int m = tid % 96;
        int s = m / 32;
        int t = m % 32;
        float u  = (t + 0.5f) * (1.f / 32.f);
        float v  = 1.f - u;
        float b0 = v * v * v;
        float b1 = 3.f * u * v * v;
        float b2 = 3.f * u * u * v;
        float b3 = u * u * u;
        const float* cp = out + CP_OFF + b * 48 + p * 24 + s * 8;
        float cx = b0 * cp[0] + b1 * cp[2] + b2 * cp[4] + b3 * cp[6];
        float cy = b0 * cp[1] + b1 * cp[3] + b2 * cp[5] + b3 * cp[7];
        cur[tid] = make_float2(cx, cy);
    } else if (tid < 196) {
        int i = tid - 192;
        wa[i] = (i < 2) ? 0.5f * out[W_OFF + b * 2 + i]
                        : out[A_OFF + b * 2 + (i - 2)];
    }
    __syncthreads();

    if (tid < 196) {
        int Y = tid / 28, X = tid - Y * 28;
        float px0 = X + 0.25f;
        float py0 = (7 * q + Y) + 0.25f;

        float mA[4] = {1e30f, 1e30f, 1e30f, 1e30f};
        float mB[4] = {1e30f, 1e30f, 1e30f, 1e30f};
        #pragma unroll 4
        for (int m = 0; m < 96; ++m) {
            float2 c = cur[m];
            float dx0 = px0 - c.x, dy0 = py0 - c.y;
            float dx1 = dx0 + 0.5f, dy1 = dy0 + 0.5f;
            float xx0 = dx0 * dx0, xx1 = dx1 * dx1;
            float yy0 = dy0 * dy0, yy1 = dy1 * dy1;
            mA[0] = fminf(mA[0], xx0 + yy0);
            mA[1] = fminf(mA[1], xx1 + yy0);
            mA[2] = fminf(mA[2], xx0 + yy1);
            mA[3] = fminf(mA[3], xx1 + yy1);
        }
        #pragma unroll 4
        for (int m = 96; m < 192; ++m) {
            float2 c = cur[m];
            float dx0 = px0 - c.x, dy0 = py0 - c.y;
            float dx1 = dx0 + 0.5f, dy1 = dy0 + 0.5f;
            float xx0 = dx0 * dx0, xx1 = dx1 * dx1;
            float yy0 = dy0 * dy0, yy1 = dy1 * dy1;
            mB[0] = fminf(mB[0], xx0 + yy0);
            mB[1] = fminf(mB[1], xx1 + yy0);
            mB[2] = fminf(mB[2], xx0 + yy1);
            mB[3] = fminf(mB[3], xx1 + yy1);
        }

        const float w0 = wa[0], w1 = wa[1], a0 = wa[2], a1 = wa[3];
        float v = 0.f;
        #pragma unroll
        for (int s = 0; s < 4; ++s) {
            float d0 = sqrtf(mA[s] + 1e-12f);
            float d1 = sqrtf(mB[s] + 1e-12f);
            float c0 = a0 / (1.f + expf(-2.f * (w0 - d0)));
            float c1 = a1 / (1.f + expf(-2.f * (w1 - d1)));
            v += (1.f - c0) * (1.f - c1);
        }
        out[REND_OFF + b * 784 + (7 * q + Y) * 28 + X] = 1.f - 0.25f * v;
    }
}

extern "C" void kernel_launch(void* const* d_in, const int* in_sizes, int n_in,
                              void* d_out, int out_size, void* d_ws, size_t ws_size,
                              hipStream_t stream) {
    const float* x    = (const float*)d_in[0];
    const float* eps  = (const float*)d_in[1];
    const float* e_w1 = (const float*)d_in[2];
    const float* e_b1 = (const float*)d_in[3];
    const float* e_w2 = (const float*)d_in[4];
    const float* e_b2 = (const float*)d_in[5];
    const float* w_mu = (const float*)d_in[6];
    const float* b_mu = (const float*)d_in[7];
    const float* w_lv = (const float*)d_in[8];
    const float* b_lv = (const float*)d_in[9];
    const float* d_w1 = (const float*)d_in[10];
    const float* d_b1 = (const float*)d_in[11];
    const float* d_w2 = (const float*)d_in[12];
    const float* d_b2 = (const float*)d_in[13];
    const float* p_w  = (const float*)d_in[14];
    const float* p_b  = (const float*)d_in[15];
    const float* wd_w = (const float*)d_in[16];
    const float* wd_b = (const float*)d_in[17];
    const float* a_w  = (const float*)d_in[18];
    const float* a_b  = (const float*)d_in[19];
    float* out = (float*)d_out;
    unsigned* wsu = (unsigned*)d_ws;

    hipLaunchKernelGGL(conv_q, dim3(432), dim3(256), 0, stream,
                       e_w1, e_w2, w_mu, w_lv, d_w1, d_w2, p_w, wd_w, a_w, wsu);
    hipLaunchKernelGGL(vae_mlp, dim3(128), dim3(1024), 0, stream,
                       x, eps, e_b1, e_b2, b_mu, b_lv, d_b1, d_b2,
                       p_b, wd_b, a_b, wsu, out);
    hipLaunchKernelGGL(vae_render, dim3(128, 4), dim3(256), 0, stream, out);
}